// Round 1
// baseline (395.581 us; speedup 1.0000x reference)
//
#include <hip/hip_runtime.h>

typedef float  f32x4  __attribute__((ext_vector_type(4)));
typedef short  s16x8  __attribute__((ext_vector_type(8)));
typedef short  s16x4  __attribute__((ext_vector_type(4)));

__device__ __forceinline__ short f2bf(float f) {
  unsigned u = __float_as_uint(f);
  u += 0x7fffu + ((u >> 16) & 1u);   // RNE
  return (short)(u >> 16);
}
__device__ __forceinline__ float bf2f(unsigned short us) {
  return __uint_as_float(((unsigned)us) << 16);
}
__device__ __forceinline__ float tanh_fast(float x) {
  const float e = __expf(2.0f * x);
  return 1.0f - 2.0f / (e + 1.0f);
}

// ---------------------------------------------------------------------------
// K0: convert+transpose weights to bf16 once.
//  Awt[128][256]  <- aw1(256x128)      blocks [0,128)
//  Wpt[256][768]  <- [we;wv;wp]^T      blocks [128,896)
//  W1t[512][768]  <- w1^T              blocks [896,2432)
//  W2t[256][512]  <- w2^T              blocks [2432,2944)
// ---------------------------------------------------------------------------
__global__ __launch_bounds__(256) void k_cvtw(
    const float* __restrict__ aw1, const float* __restrict__ we, const float* __restrict__ wv,
    const float* __restrict__ wp, const float* __restrict__ w1, const float* __restrict__ w2,
    unsigned short* __restrict__ Awt, unsigned short* __restrict__ Wpt,
    unsigned short* __restrict__ W1t, unsigned short* __restrict__ W2t) {
  const int b = blockIdx.x, tid = threadIdx.x;
  if (b < 128) {
    const int e = b * 256 + tid, n = e >> 8, k = e & 255;
    Awt[e] = (unsigned short)f2bf(aw1[k * 128 + n]);
  } else if (b < 896) {
    const int e = (b - 128) * 256 + tid, n = e / 768, k = e % 768;
    const int part = k >> 8, kk = k & 255;
    const float* W = (part == 0) ? we : ((part == 1) ? wv : wp);
    Wpt[e] = (unsigned short)f2bf(W[kk * 256 + n]);
  } else if (b < 2432) {
    const int e = (b - 896) * 256 + tid, n = e / 768, k = e % 768;
    W1t[e] = (unsigned short)f2bf(w1[k * 512 + n]);
  } else {
    const int e = (b - 2432) * 256 + tid, n = e >> 9, k = e & 511;
    W2t[e] = (unsigned short)f2bf(w2[k * 256 + n]);
  }
}

// ---------------------------------------------------------------------------
// K1: fused attention-score (bf16 MFMA) + segment pooling.  (unchanged)
// ---------------------------------------------------------------------------
__global__ __launch_bounds__(256) void k_score_pool(
    const float* __restrict__ x, const int* __restrict__ batch, const int* __restrict__ mask,
    const unsigned short* __restrict__ Awt, const float* __restrict__ ab1,
    const float* __restrict__ aw2, const float* __restrict__ ab2,
    float* __restrict__ P, float* __restrict__ EX, float* __restrict__ ZC,
    int nnodes) {
  __shared__ __align__(16) short xs[2][32][264];   // bf16 x, dbuf (33.8 KB)
  __shared__ __align__(16) float sred[4][32];
  __shared__ __align__(16) float e_sh[4][32];      // per-wave copies (no barrier needed)
  __shared__ int st_all[320];                      // seg*4+type for block's nodes

  const int tid  = threadIdx.x;
  const int lane = tid & 63;
  const int w    = tid >> 6;    // wave -> score cols [32w, 32w+32)
  const int quad = lane >> 4;
  const int l15  = lane & 15;

  s16x8 bfrag[8][2];
  float ab1v[2], aw2v[2];
#pragma unroll
  for (int ct = 0; ct < 2; ++ct) {
    const int col = w * 32 + ct * 16 + l15;
    ab1v[ct] = ab1[col];
    aw2v[ct] = aw2[col];
    const s16x8* bp = reinterpret_cast<const s16x8*>(Awt + (size_t)col * 256);
#pragma unroll
    for (int kt = 0; kt < 8; ++kt) bfrag[kt][ct] = bp[kt * 4 + quad];
  }
  const float ab2v = ab2[0];

  const int tiles = nnodes >> 5;                                // 6250
  const int tpb   = (tiles + (int)gridDim.x - 1) / (int)gridDim.x;
  const int t_beg = blockIdx.x * tpb;
  const int t_end = min(t_beg + tpb, tiles);
  if (t_beg >= t_end) return;   // whole-block exit: no barrier mismatch

  { // preload seg/type for the whole block range
    const int nodes0 = t_beg * 32, nblk = (t_end - t_beg) * 32;
    for (int i = tid; i < nblk; i += 256) {
      const int g = nodes0 + i;
      st_all[i] = batch[g] * 4 + mask[g * 3 + 1] + 2 * mask[g * 3 + 2];
    }
  }

  f32x4 stg[8];
  auto load_regs = [&](int tile) {
    const f32x4* xp = reinterpret_cast<const f32x4*>(x + (size_t)tile * 8192);
#pragma unroll
    for (int i = 0; i < 8; ++i) stg[i] = xp[tid + 256 * i];
  };
  const int col4 = (tid & 63) * 4;
  auto cvt_write = [&](int b) {
#pragma unroll
    for (int i = 0; i < 8; ++i) {
      const int row = (tid >> 6) + 4 * i;
      s16x4 v; v[0] = f2bf(stg[i][0]); v[1] = f2bf(stg[i][1]);
      v[2] = f2bf(stg[i][2]); v[3] = f2bf(stg[i][3]);
      *reinterpret_cast<s16x4*>(&xs[b][row][col4]) = v;
    }
  };

  load_regs(t_beg);
  cvt_write(0);
  __syncthreads();   // buf0 + st_all ready

  float a0 = 0.f, a1 = 0.f, a2 = 0.f, aex = 0.f, zc = 0.f;
  int cur = -1;

  auto flush = [&]() {
    atomicAdd(&P[cur * 768 + tid], a0);
    atomicAdd(&P[cur * 768 + 256 + tid], a1);
    atomicAdd(&P[cur * 768 + 512 + tid], a2);
    atomicAdd(&EX[cur * 256 + tid], aex);
    if (tid < 4) atomicAdd(&ZC[cur * 4 + tid], zc);
    a0 = a1 = a2 = aex = zc = 0.f;
  };

  for (int tile = t_beg; tile < t_end; ++tile) {
    const int buf = (tile - t_beg) & 1;
    const bool more = (tile + 1 < t_end);
    if (more) load_regs(tile + 1);   // issue loads early: in flight all iteration

    // --- MFMA scores: 32 nodes x this wave's 32 cols ---
#pragma unroll
    for (int ng = 0; ng < 2; ++ng) {
      s16x8 af[8];
#pragma unroll
      for (int kt = 0; kt < 8; ++kt)
        af[kt] = *reinterpret_cast<const s16x8*>(&xs[buf][16 * ng + l15][kt * 32 + quad * 8]);
      float part[4] = {0.f, 0.f, 0.f, 0.f};
#pragma unroll
      for (int ct = 0; ct < 2; ++ct) {
        f32x4 acc = {0.f, 0.f, 0.f, 0.f};
#pragma unroll
        for (int kt = 0; kt < 8; ++kt)
          acc = __builtin_amdgcn_mfma_f32_16x16x32_bf16(af[kt], bfrag[kt][ct], acc, 0, 0, 0);
#pragma unroll
        for (int r = 0; r < 4; ++r)
          part[r] += tanh_fast(acc[r] + ab1v[ct]) * aw2v[ct];
      }
#pragma unroll
      for (int off = 1; off < 16; off <<= 1) {
#pragma unroll
        for (int r = 0; r < 4; ++r) part[r] += __shfl_xor(part[r], off);
      }
      if (l15 == 0) {
#pragma unroll
        for (int r = 0; r < 4; ++r) sred[w][16 * ng + quad * 4 + r] = part[r];
      }
    }
    __syncthreads();   // A: sred ready

    if (lane < 32) {
      const float s = ab2v + sred[0][lane] + sred[1][lane] + sred[2][lane] + sred[3][lane];
      e_sh[w][lane] = __expf(s);   // per-wave copy; read after in-wave write: no barrier
    }

    // --- pooling: thread d=tid over the 32 nodes ---
    const int base = (tile - t_beg) * 32;
#pragma unroll
    for (int n = 0; n < 32; ++n) {
      const int st  = st_all[base + n];     // block-uniform
      const int seg = st >> 2, t = st & 3;
      if (seg != cur) { if (cur >= 0) flush(); cur = seg; }
      const float e  = e_sh[w][n];
      const float xv = bf2f((unsigned short)xs[buf][n][tid]);
      aex += e * xv;
      if (t == 0) a0 += xv; else if (t == 1) a1 += xv; else a2 += xv;
      if (tid < 4) zc += (tid == 0) ? e : ((t == tid - 1) ? 1.f : 0.f);
    }

    if (more) cvt_write(buf ^ 1);   // consume staged regs late (latency covered)
    __syncthreads();   // B: next buf ready; protects xs/sred intervals
  }
  if (cur >= 0) flush();
}

// ---------------------------------------------------------------------------
// K2 (NEW): fused tail. One block = 16 output rows, end-to-end:
//   finalize (mean/attn) -> phys MFMA -> mlp1 MFMA+silu -> mlp2 MFMA -> out.
// comb and h live only in LDS; no global round-trips, no extra dispatches.
// Convert points (f32->bf16) are identical to the old 4-kernel chain, so
// numerics are bit-identical.
// ---------------------------------------------------------------------------
__global__ __launch_bounds__(512) void k_tail(
    const float* __restrict__ P, const float* __restrict__ EX, const float* __restrict__ ZC,
    const unsigned short* __restrict__ Wpt, const unsigned short* __restrict__ W1t,
    const unsigned short* __restrict__ W2t,
    const float* __restrict__ be, const float* __restrict__ bv, const float* __restrict__ bp,
    const float* __restrict__ b1, const float* __restrict__ b2,
    float* __restrict__ out) {
  __shared__ __align__(16) short asP[16][776];   // P rows, bf16 (A for phys)
  __shared__ __align__(16) short asC[16][776];   // comb rows, bf16 (A for mlp1)
  __shared__ __align__(16) short ash[16][520];   // h rows, bf16 (A for mlp2)

  const int tid = threadIdx.x, lane = tid & 63, w = tid >> 6;   // 8 waves
  const int quad = lane >> 4, l15 = lane & 15;
  const int rowbase = blockIdx.x * 16;

  // --- stage P (16x768) as bf16 ---
  const f32x4* ap = reinterpret_cast<const f32x4*>(P + (size_t)rowbase * 768);
#pragma unroll
  for (int i = 0; i < 6; ++i) {
    const int ci = tid + 512 * i;
    f32x4 v = ap[ci];
    const int row = ci / 192, c4 = (ci % 192) * 4;
    s16x4 b; b[0] = f2bf(v[0]); b[1] = f2bf(v[1]); b[2] = f2bf(v[2]); b[3] = f2bf(v[3]);
    *reinterpret_cast<s16x4*>(&asP[row][c4]) = b;
  }
  __syncthreads();   // asP ready

  // --- finalize: comb cols [0,512) = mean | attn (fp32 math, then f2bf) ---
  {
    const int d  = tid & 255;
    const int r0 = (tid >> 8) * 8;
#pragma unroll
    for (int rr = 0; rr < 8; ++rr) {
      const int r = r0 + rr, row = rowbase + r;
      const float z   = ZC[row * 4 + 0];
      const float cnt = ZC[row * 4 + 1] + ZC[row * 4 + 2] + ZC[row * 4 + 3];
      const float mp  = (P[(size_t)row * 768 + d] + P[(size_t)row * 768 + 256 + d] +
                         P[(size_t)row * 768 + 512 + d]) / cnt;
      const float at  = EX[(size_t)row * 256 + d] / z;
      asC[r][d]       = f2bf(mp);
      asC[r][256 + d] = f2bf(at);
    }
  }

  // --- phys: comb cols [512,768) = P @ Wpt^T + count-weighted biases ---
#pragma unroll 1
  for (int cg = 0; cg < 2; ++cg) {
    const int col = cg * 128 + w * 16 + l15;
    s16x8 bfr[24];
    const s16x8* bpf = reinterpret_cast<const s16x8*>(Wpt + (size_t)col * 768);
#pragma unroll
    for (int kt = 0; kt < 24; ++kt) bfr[kt] = bpf[kt * 4 + quad];
    f32x4 acc = {0.f, 0.f, 0.f, 0.f};
#pragma unroll
    for (int kt = 0; kt < 24; ++kt) {
      s16x8 af = *reinterpret_cast<const s16x8*>(&asP[l15][kt * 32 + quad * 8]);
      acc = __builtin_amdgcn_mfma_f32_16x16x32_bf16(af, bfr[kt], acc, 0, 0, 0);
    }
    const float ben = be[col], bvn = bv[col], bpn = bp[col];
#pragma unroll
    for (int r = 0; r < 4; ++r) {
      const int rl = quad * 4 + r, row = rowbase + rl;
      const float v = acc[r] + ZC[row * 4 + 1] * ben + ZC[row * 4 + 2] * bvn + ZC[row * 4 + 3] * bpn;
      asC[rl][512 + col] = f2bf(v);
    }
  }
  __syncthreads();   // asC (comb bf16) ready

  // --- mlp1: h = silu(comb @ W1 + b1), 512 cols ---
#pragma unroll 1
  for (int cg = 0; cg < 4; ++cg) {
    const int col = cg * 128 + w * 16 + l15;
    s16x8 bfr[24];
    const s16x8* bpf = reinterpret_cast<const s16x8*>(W1t + (size_t)col * 768);
#pragma unroll
    for (int kt = 0; kt < 24; ++kt) bfr[kt] = bpf[kt * 4 + quad];
    f32x4 acc = {0.f, 0.f, 0.f, 0.f};
#pragma unroll
    for (int kt = 0; kt < 24; ++kt) {
      s16x8 af = *reinterpret_cast<const s16x8*>(&asC[l15][kt * 32 + quad * 8]);
      acc = __builtin_amdgcn_mfma_f32_16x16x32_bf16(af, bfr[kt], acc, 0, 0, 0);
    }
    const float bn = b1[col];
#pragma unroll
    for (int r = 0; r < 4; ++r) {
      const int rl = quad * 4 + r;
      const float v = acc[r] + bn;
      ash[rl][col] = f2bf(v / (1.f + __expf(-v)));
    }
  }
  __syncthreads();   // ash (h bf16) ready

  // --- mlp2: out = h @ W2 + b2, 256 cols ---
#pragma unroll 1
  for (int cg = 0; cg < 2; ++cg) {
    const int col = cg * 128 + w * 16 + l15;
    s16x8 bfr[16];
    const s16x8* bpf = reinterpret_cast<const s16x8*>(W2t + (size_t)col * 512);
#pragma unroll
    for (int kt = 0; kt < 16; ++kt) bfr[kt] = bpf[kt * 4 + quad];
    f32x4 acc = {0.f, 0.f, 0.f, 0.f};
#pragma unroll
    for (int kt = 0; kt < 16; ++kt) {
      s16x8 af = *reinterpret_cast<const s16x8*>(&ash[l15][kt * 32 + quad * 8]);
      acc = __builtin_amdgcn_mfma_f32_16x16x32_bf16(af, bfr[kt], acc, 0, 0, 0);
    }
    const float bn = b2[col];
#pragma unroll
    for (int r = 0; r < 4; ++r) {
      const int rl = quad * 4 + r;
      out[(size_t)(rowbase + rl) * 256 + col] = acc[r] + bn;
    }
  }
}

// ---------------------------------------------------------------------------
extern "C" void kernel_launch(void* const* d_in, const int* in_sizes, int n_in,
                              void* d_out, int out_size, void* d_ws, size_t ws_size,
                              hipStream_t stream) {
  const float* x    = (const float*)d_in[0];
  const int*   batch= (const int*)  d_in[1];
  const int*   mask = (const int*)  d_in[2];
  const float* aw1  = (const float*)d_in[4];
  const float* ab1  = (const float*)d_in[5];
  const float* aw2  = (const float*)d_in[6];
  const float* ab2  = (const float*)d_in[7];
  const float* we   = (const float*)d_in[8];
  const float* be   = (const float*)d_in[9];
  const float* wv   = (const float*)d_in[10];
  const float* bv   = (const float*)d_in[11];
  const float* wp   = (const float*)d_in[12];
  const float* bp   = (const float*)d_in[13];
  const float* w1   = (const float*)d_in[14];
  const float* b1   = (const float*)d_in[15];
  const float* w2   = (const float*)d_in[16];
  const float* b2   = (const float*)d_in[17];
  float* out = (float*)d_out;
  const int nn = in_sizes[1];   // 200000 nodes

  float* ws = (float*)d_ws;
  float* P    = ws;                         // 1024*768
  float* EXs  = P    + 786432;              // 1024*256
  float* ZCs  = EXs  + 262144;              // 1024*4 [z,c0,c1,c2]
  unsigned short* Awt = (unsigned short*)(ZCs + 4096);      // 128*256
  unsigned short* Wpt = Awt + 32768;        // 256*768
  unsigned short* W1t = Wpt + 196608;       // 512*768
  unsigned short* W2t = W1t + 393216;       // 256*512

  hipMemsetAsync(P, 0, (size_t)(786432 + 262144 + 4096) * sizeof(float), stream);

  k_cvtw      <<<2944, 256, 0, stream>>>(aw1, we, wv, wp, w1, w2, Awt, Wpt, W1t, W2t);
  k_score_pool<<<1024, 256, 0, stream>>>(x, batch, mask, Awt, ab1, aw2, ab2, P, EXs, ZCs, nn);
  k_tail      <<<64, 512, 0, stream>>>(P, EXs, ZCs, Wpt, W1t, W2t, be, bv, bp, b1, b2, out);
}

// Round 2
// 348.680 us; speedup vs baseline: 1.1345x; 1.1345x over previous
//
#include <hip/hip_runtime.h>

typedef float  f32x4  __attribute__((ext_vector_type(4)));
typedef short  s16x8  __attribute__((ext_vector_type(8)));
typedef short  s16x4  __attribute__((ext_vector_type(4)));

__device__ __forceinline__ short f2bf(float f) {
  unsigned u = __float_as_uint(f);
  u += 0x7fffu + ((u >> 16) & 1u);   // RNE
  return (short)(u >> 16);
}
__device__ __forceinline__ float bf2f(unsigned short us) {
  return __uint_as_float(((unsigned)us) << 16);
}
__device__ __forceinline__ float tanh_fast(float x) {
  const float e = __expf(2.0f * x);
  return 1.0f - 2.0f / (e + 1.0f);
}

// ---------------------------------------------------------------------------
// K0: convert+transpose weights to bf16 once.
// ---------------------------------------------------------------------------
__global__ __launch_bounds__(256) void k_cvtw(
    const float* __restrict__ aw1, const float* __restrict__ we, const float* __restrict__ wv,
    const float* __restrict__ wp, const float* __restrict__ w1, const float* __restrict__ w2,
    unsigned short* __restrict__ Awt, unsigned short* __restrict__ Wpt,
    unsigned short* __restrict__ W1t, unsigned short* __restrict__ W2t) {
  const int b = blockIdx.x, tid = threadIdx.x;
  if (b < 128) {
    const int e = b * 256 + tid, n = e >> 8, k = e & 255;
    Awt[e] = (unsigned short)f2bf(aw1[k * 128 + n]);
  } else if (b < 896) {
    const int e = (b - 128) * 256 + tid, n = e / 768, k = e % 768;
    const int part = k >> 8, kk = k & 255;
    const float* W = (part == 0) ? we : ((part == 1) ? wv : wp);
    Wpt[e] = (unsigned short)f2bf(W[kk * 256 + n]);
  } else if (b < 2432) {
    const int e = (b - 896) * 256 + tid, n = e / 768, k = e % 768;
    W1t[e] = (unsigned short)f2bf(w1[k * 512 + n]);
  } else {
    const int e = (b - 2432) * 256 + tid, n = e >> 9, k = e & 511;
    W2t[e] = (unsigned short)f2bf(w2[k * 256 + n]);
  }
}

// ---------------------------------------------------------------------------
// K1: fused attention-score (bf16 MFMA) + MFMA-based segment pooling.
// Pooling = per-tile GEMM: A(16x32) rows {e_hi, e_lo, m0, m1, m2, 0...} x
// B(32x256) = x-tile, accumulated in MFMA C across tiles; segment runs
// handled by masking the A-fragment. B staged frag-major in xsB (b128 r/w).
// ---------------------------------------------------------------------------
__global__ __launch_bounds__(256, 2) void k_score_pool(
    const float* __restrict__ x, const int* __restrict__ batch, const int* __restrict__ mask,
    const unsigned short* __restrict__ Awt, const float* __restrict__ ab1,
    const float* __restrict__ aw2, const float* __restrict__ ab2,
    float* __restrict__ P, float* __restrict__ EX, float* __restrict__ ZC,
    int nnodes) {
  __shared__ __align__(16) short xs[32][264];    // bf16 x row-major (score A-frags) 16.9KB
  __shared__ __align__(16) short xsB[2][8192];   // frag-major [g][kq][l15][j], dbuf, 32KB
  __shared__ __align__(16) float sred[4][32];
  __shared__ __align__(16) short em[16][40];     // pooling A rows: ehi,elo,m0,m1,m2,0..
  __shared__ int st_all[320];                    // seg*4+type

  const int tid  = threadIdx.x;
  const int lane = tid & 63;
  const int w    = tid >> 6;    // wave -> score cols [32w, 32w+32)
  const int quad = lane >> 4;
  const int l15  = lane & 15;

  // score B-frags from pre-transposed bf16 aw1
  s16x8 bfrag[8][2];
  float ab1v[2], aw2v[2];
#pragma unroll
  for (int ct = 0; ct < 2; ++ct) {
    const int col = w * 32 + ct * 16 + l15;
    ab1v[ct] = ab1[col];
    aw2v[ct] = aw2[col];
    const s16x8* bp = reinterpret_cast<const s16x8*>(Awt + (size_t)col * 256);
#pragma unroll
    for (int kt = 0; kt < 8; ++kt) bfrag[kt][ct] = bp[kt * 4 + quad];
  }
  const float ab2v = ab2[0];

  const int tiles = nnodes >> 5;                                // 6250
  const int t_beg = (int)(((long long)blockIdx.x * tiles) / (long long)gridDim.x);
  const int t_end = (int)(((long long)(blockIdx.x + 1) * tiles) / (long long)gridDim.x);
  if (t_beg >= t_end) return;

  { // preload seg/type for the whole block range; zero em (rows 5..15 stay 0)
    const int nodes0 = t_beg * 32, nblk = (t_end - t_beg) * 32;
    for (int i = tid; i < nblk; i += 256) {
      const int g = nodes0 + i;
      st_all[i] = batch[g] * 4 + mask[g * 3 + 1] + 2 * mask[g * 3 + 2];
    }
    for (int i = tid; i < 640; i += 256) (&em[0][0])[i] = 0;
  }

  f32x4 stg[8];
  auto load_regs = [&](int tile) {
    const f32x4* xp = reinterpret_cast<const f32x4*>(x + (size_t)tile * 8192);
    // thread holds rows 8w..8w+7 (consecutive nodes) at d0 = lane*4
#pragma unroll
    for (int i = 0; i < 8; ++i) stg[i] = xp[(8 * w + i) * 64 + lane];
  };
  auto cvt_write = [&](int bB) {
    s16x4 xv[8];
#pragma unroll
    for (int i = 0; i < 8; ++i) {
      xv[i][0] = f2bf(stg[i][0]); xv[i][1] = f2bf(stg[i][1]);
      xv[i][2] = f2bf(stg[i][2]); xv[i][3] = f2bf(stg[i][3]);
    }
#pragma unroll
    for (int i = 0; i < 8; ++i)
      *reinterpret_cast<s16x4*>(&xs[8 * w + i][lane * 4]) = xv[i];
    const int gb = (lane >> 2) * 4 + w;        // g*4 + kquad(=w)
    const int lb = (lane & 3) * 4;
#pragma unroll
    for (int q = 0; q < 4; ++q) {
      s16x8 v;
#pragma unroll
      for (int j = 0; j < 8; ++j) v[j] = xv[j][q];
      *reinterpret_cast<s16x8*>(&xsB[bB][(gb * 16 + lb + q) * 8]) = v;
    }
  };

  load_regs(t_beg);
  cvt_write(0);
  __syncthreads();   // xs/xsB[0] + st_all + em-zeros ready

  const f32x4 zero4 = {0.f, 0.f, 0.f, 0.f};
  f32x4 accB[4] = {zero4, zero4, zero4, zero4};
  float zA = 0.f, c0A = 0.f, c1A = 0.f, c2A = 0.f;
  int cur = -1;

  auto flushB = [&]() {
#pragma unroll
    for (int c = 0; c < 4; ++c) {
      const int col = w * 64 + c * 16 + l15;
      if (quad == 0) {
        atomicAdd(&EX[cur * 256 + col], accB[c][0] + accB[c][1]);   // rows 0,1 = ehi,elo
        atomicAdd(&P[cur * 768 + col], accB[c][2]);                 // row 2 = type0
        atomicAdd(&P[cur * 768 + 256 + col], accB[c][3]);           // row 3 = type1
      } else if (quad == 1) {
        atomicAdd(&P[cur * 768 + 512 + col], accB[c][0]);           // row 4 = type2
      }
      accB[c] = zero4;
    }
    if (w == 0) {
      if (lane < 4) {
        const float v = (lane == 0) ? zA : ((lane == 1) ? c0A : ((lane == 2) ? c1A : c2A));
        atomicAdd(&ZC[cur * 4 + lane], v);
      }
      zA = c0A = c1A = c2A = 0.f;
    }
  };

  for (int tile = t_beg; tile < t_end; ++tile) {
    const int buf = (tile - t_beg) & 1;
    const bool more = (tile + 1 < t_end);
    if (more) load_regs(tile + 1);   // in flight across the whole iteration

    // --- MFMA scores: 32 nodes x this wave's 32 cols ---
#pragma unroll
    for (int ng = 0; ng < 2; ++ng) {
      s16x8 af[8];
#pragma unroll
      for (int kt = 0; kt < 8; ++kt)
        af[kt] = *reinterpret_cast<const s16x8*>(&xs[16 * ng + l15][kt * 32 + quad * 8]);
      float part[4] = {0.f, 0.f, 0.f, 0.f};
#pragma unroll
      for (int ct = 0; ct < 2; ++ct) {
        f32x4 acc = {0.f, 0.f, 0.f, 0.f};
#pragma unroll
        for (int kt = 0; kt < 8; ++kt)
          acc = __builtin_amdgcn_mfma_f32_16x16x32_bf16(af[kt], bfrag[kt][ct], acc, 0, 0, 0);
#pragma unroll
        for (int r = 0; r < 4; ++r)
          part[r] += tanh_fast(acc[r] + ab1v[ct]) * aw2v[ct];
      }
#pragma unroll
      for (int off = 1; off < 16; off <<= 1) {
#pragma unroll
        for (int r = 0; r < 4; ++r) part[r] += __shfl_xor(part[r], off);
      }
      if (l15 == 0) {
#pragma unroll
        for (int r = 0; r < 4; ++r) sred[w][16 * ng + quad * 4 + r] = part[r];
      }
    }
    __syncthreads();   // A: sred ready; xs reads done (writes allowed after)

    const int base = (tile - t_beg) * 32;

    // per-wave: e (f32) + em rows (all waves write identical values: benign)
    float e_f = 0.f;
    int myt = 3;
    if (lane < 32) {
      const float s = ab2v + sred[0][lane] + sred[1][lane] + sred[2][lane] + sred[3][lane];
      e_f = __expf(s);
      const unsigned short hi = (unsigned short)f2bf(e_f);
      const unsigned short lo = (unsigned short)f2bf(e_f - bf2f(hi));
      myt = st_all[base + lane] & 3;
      em[0][lane] = (short)hi;
      em[1][lane] = (short)lo;
      em[2][lane] = (myt == 0) ? (short)0x3f80 : (short)0;
      em[3][lane] = (myt == 1) ? (short)0x3f80 : (short)0;
      em[4][lane] = (myt == 2) ? (short)0x3f80 : (short)0;
    }
    const int myseg = (lane < 32) ? (st_all[base + lane] >> 2) : 0x7fffffff;

    s16x8 emf = *reinterpret_cast<const s16x8*>(&em[l15][quad * 8]);   // pooling A-frag
    s16x8 bfB[4];                                                       // pooling B-frags
#pragma unroll
    for (int c = 0; c < 4; ++c)
      bfB[c] = *reinterpret_cast<const s16x8*>(
          &xsB[buf][(((w * 4 + c) * 4 + quad) * 16 + l15) * 8]);

    int n0 = 0;
    while (n0 < 32) {
      const int seg = st_all[base + n0] >> 2;                    // uniform
      const unsigned long long diff = __ballot(lane < 32 && myseg != seg) >> n0;
      const int n1 = (diff == 0) ? 32 : n0 + (int)__builtin_ctzll(diff);
      if (seg != cur) { if (cur >= 0) flushB(); cur = seg; }
      s16x8 af;
      const int kb = quad * 8;
#pragma unroll
      for (int j = 0; j < 8; ++j) {
        const int k = kb + j;
        af[j] = (k >= n0 && k < n1) ? emf[j] : (short)0;
      }
#pragma unroll
      for (int c = 0; c < 4; ++c)
        accB[c] = __builtin_amdgcn_mfma_f32_16x16x32_bf16(af, bfB[c], accB[c], 0, 0, 0);
      if (w == 0) {   // z and type counts (exact, f32/int path)
        const bool inrun = (lane >= n0 && lane < n1 && lane < 32);
        float ee = inrun ? e_f : 0.f;
#pragma unroll
        for (int off = 1; off < 32; off <<= 1) ee += __shfl_xor(ee, off);
        const unsigned long long b0 = __ballot(inrun && myt == 0);
        const unsigned long long b1 = __ballot(inrun && myt == 1);
        const unsigned long long b2 = __ballot(inrun && myt == 2);
        zA  += ee;
        c0A += (float)__popcll(b0);
        c1A += (float)__popcll(b1);
        c2A += (float)__popcll(b2);
      }
      n0 = n1;
    }

    if (more) cvt_write(buf ^ 1);   // consume staged regs late (latency covered)
    __syncthreads();   // B: next xs/xsB ready
  }
  if (cur >= 0) flushB();
}

// ---------------------------------------------------------------------------
// K2: finalize mean/attn pools into combined[:, 0:512]
// ---------------------------------------------------------------------------
__global__ __launch_bounds__(256) void k_finalize(
    const float* __restrict__ P, const float* __restrict__ EX,
    const float* __restrict__ ZC, float* __restrict__ comb) {
  const int b = blockIdx.x, d = threadIdx.x;
  const float p0 = P[b * 768 + d], p1 = P[b * 768 + 256 + d], p2 = P[b * 768 + 512 + d];
  const float cnt = ZC[b * 4 + 1] + ZC[b * 4 + 2] + ZC[b * 4 + 3];
  comb[(size_t)b * 768 + d]       = (p0 + p1 + p2) / cnt;
  comb[(size_t)b * 768 + 256 + d] = EX[b * 256 + d] / ZC[b * 4];
}

// ---------------------------------------------------------------------------
// MFMA GEMM blocks (16 rows x 64 cols), as r0 (proven).
// ---------------------------------------------------------------------------
__global__ __launch_bounds__(256) void k_phys(
    const float* __restrict__ P, const unsigned short* __restrict__ Wpt,
    const float* __restrict__ be, const float* __restrict__ bv, const float* __restrict__ bp,
    const float* __restrict__ ZC, float* __restrict__ comb) {
  __shared__ __align__(16) short as16[16][776];
  const int tid = threadIdx.x, lane = tid & 63, w = tid >> 6;
  const int quad = lane >> 4, l15 = lane & 15;
  const int rowbase = blockIdx.x * 16;
  const int col = blockIdx.y * 64 + w * 16 + l15;

  s16x8 bfr[24];
  const s16x8* bpf = reinterpret_cast<const s16x8*>(Wpt + (size_t)col * 768);
#pragma unroll
  for (int kt = 0; kt < 24; ++kt) bfr[kt] = bpf[kt * 4 + quad];

  const f32x4* ap = reinterpret_cast<const f32x4*>(P + (size_t)rowbase * 768);
#pragma unroll
  for (int i = 0; i < 12; ++i) {
    const int ci = tid + 256 * i;
    f32x4 v = ap[ci];
    const int row = ci / 192, c4 = (ci % 192) * 4;
    s16x4 b; b[0] = f2bf(v[0]); b[1] = f2bf(v[1]); b[2] = f2bf(v[2]); b[3] = f2bf(v[3]);
    *reinterpret_cast<s16x4*>(&as16[row][c4]) = b;
  }
  __syncthreads();

  f32x4 acc = {0.f, 0.f, 0.f, 0.f};
#pragma unroll
  for (int kt = 0; kt < 24; ++kt) {
    s16x8 af = *reinterpret_cast<const s16x8*>(&as16[l15][kt * 32 + quad * 8]);
    acc = __builtin_amdgcn_mfma_f32_16x16x32_bf16(af, bfr[kt], acc, 0, 0, 0);
  }
  const float ben = be[col], bvn = bv[col], bpn = bp[col];
#pragma unroll
  for (int r = 0; r < 4; ++r) {
    const int row = rowbase + quad * 4 + r;
    const float v = acc[r] + ZC[row * 4 + 1] * ben + ZC[row * 4 + 2] * bvn + ZC[row * 4 + 3] * bpn;
    comb[(size_t)row * 768 + 512 + col] = v;
  }
}

__global__ __launch_bounds__(256) void k_mlp1(
    const float* __restrict__ A, const unsigned short* __restrict__ W1t,
    const float* __restrict__ b1, float* __restrict__ H) {
  __shared__ __align__(16) short as16[16][776];
  const int tid = threadIdx.x, lane = tid & 63, w = tid >> 6;
  const int quad = lane >> 4, l15 = lane & 15;
  const int rowbase = blockIdx.x * 16;
  const int col = blockIdx.y * 64 + w * 16 + l15;

  s16x8 bfr[24];
  const s16x8* bpf = reinterpret_cast<const s16x8*>(W1t + (size_t)col * 768);
#pragma unroll
  for (int kt = 0; kt < 24; ++kt) bfr[kt] = bpf[kt * 4 + quad];

  const f32x4* ap = reinterpret_cast<const f32x4*>(A + (size_t)rowbase * 768);
#pragma unroll
  for (int i = 0; i < 12; ++i) {
    const int ci = tid + 256 * i;
    f32x4 v = ap[ci];
    const int row = ci / 192, c4 = (ci % 192) * 4;
    s16x4 b; b[0] = f2bf(v[0]); b[1] = f2bf(v[1]); b[2] = f2bf(v[2]); b[3] = f2bf(v[3]);
    *reinterpret_cast<s16x4*>(&as16[row][c4]) = b;
  }
  __syncthreads();

  f32x4 acc = {0.f, 0.f, 0.f, 0.f};
#pragma unroll
  for (int kt = 0; kt < 24; ++kt) {
    s16x8 af = *reinterpret_cast<const s16x8*>(&as16[l15][kt * 32 + quad * 8]);
    acc = __builtin_amdgcn_mfma_f32_16x16x32_bf16(af, bfr[kt], acc, 0, 0, 0);
  }
  const float bn = b1[col];
#pragma unroll
  for (int r = 0; r < 4; ++r) {
    const int row = rowbase + quad * 4 + r;
    const float v = acc[r] + bn;
    H[(size_t)row * 512 + col] = v / (1.f + __expf(-v));
  }
}

__global__ __launch_bounds__(256) void k_mlp2(
    const float* __restrict__ A, const unsigned short* __restrict__ W2t,
    const float* __restrict__ b2, float* __restrict__ out) {
  __shared__ __align__(16) short as16[16][520];
  const int tid = threadIdx.x, lane = tid & 63, w = tid >> 6;
  const int quad = lane >> 4, l15 = lane & 15;
  const int rowbase = blockIdx.x * 16;
  const int col = blockIdx.y * 64 + w * 16 + l15;

  s16x8 bfr[16];
  const s16x8* bpf = reinterpret_cast<const s16x8*>(W2t + (size_t)col * 512);
#pragma unroll
  for (int kt = 0; kt < 16; ++kt) bfr[kt] = bpf[kt * 4 + quad];

  const f32x4* ap = reinterpret_cast<const f32x4*>(A + (size_t)rowbase * 512);
#pragma unroll
  for (int i = 0; i < 8; ++i) {
    const int ci = tid + 256 * i;
    f32x4 v = ap[ci];
    const int row = ci >> 7, c4 = (ci & 127) * 4;
    s16x4 b; b[0] = f2bf(v[0]); b[1] = f2bf(v[1]); b[2] = f2bf(v[2]); b[3] = f2bf(v[3]);
    *reinterpret_cast<s16x4*>(&as16[row][c4]) = b;
  }
  __syncthreads();

  f32x4 acc = {0.f, 0.f, 0.f, 0.f};
#pragma unroll
  for (int kt = 0; kt < 16; ++kt) {
    s16x8 af = *reinterpret_cast<const s16x8*>(&as16[l15][kt * 32 + quad * 8]);
    acc = __builtin_amdgcn_mfma_f32_16x16x32_bf16(af, bfr[kt], acc, 0, 0, 0);
  }
  const float bn = b2[col];
#pragma unroll
  for (int r = 0; r < 4; ++r) {
    const int row = rowbase + quad * 4 + r;
    out[(size_t)row * 256 + col] = acc[r] + bn;
  }
}

// ---------------------------------------------------------------------------
extern "C" void kernel_launch(void* const* d_in, const int* in_sizes, int n_in,
                              void* d_out, int out_size, void* d_ws, size_t ws_size,
                              hipStream_t stream) {
  const float* x    = (const float*)d_in[0];
  const int*   batch= (const int*)  d_in[1];
  const int*   mask = (const int*)  d_in[2];
  const float* aw1  = (const float*)d_in[4];
  const float* ab1  = (const float*)d_in[5];
  const float* aw2  = (const float*)d_in[6];
  const float* ab2  = (const float*)d_in[7];
  const float* we   = (const float*)d_in[8];
  const float* be   = (const float*)d_in[9];
  const float* wv   = (const float*)d_in[10];
  const float* bv   = (const float*)d_in[11];
  const float* wp   = (const float*)d_in[12];
  const float* bp   = (const float*)d_in[13];
  const float* w1   = (const float*)d_in[14];
  const float* b1   = (const float*)d_in[15];
  const float* w2   = (const float*)d_in[16];
  const float* b2   = (const float*)d_in[17];
  float* out = (float*)d_out;
  const int nn = in_sizes[1];   // 200000 nodes

  float* ws = (float*)d_ws;
  float* P    = ws;                         // 1024*768
  float* EXs  = P    + 786432;              // 1024*256
  float* ZCs  = EXs  + 262144;              // 1024*4 [z,c0,c1,c2]
  float* comb = ZCs  + 4096;                // 1024*768
  float* hbuf = comb + 786432;              // 1024*512
  unsigned short* Awt = (unsigned short*)(hbuf + 524288);   // 128*256
  unsigned short* Wpt = Awt + 32768;        // 256*768
  unsigned short* W1t = Wpt + 196608;       // 512*768
  unsigned short* W2t = W1t + 393216;       // 256*512

  hipMemsetAsync(P, 0, (size_t)(786432 + 262144 + 4096) * sizeof(float), stream);

  k_cvtw      <<<2944, 256, 0, stream>>>(aw1, we, wv, wp, w1, w2, Awt, Wpt, W1t, W2t);
  k_score_pool<<<1024, 256, 0, stream>>>(x, batch, mask, Awt, ab1, aw2, ab2, P, EXs, ZCs, nn);
  k_finalize  <<<1024, 256, 0, stream>>>(P, EXs, ZCs, comb);
  k_phys      <<<dim3(64, 4), 256, 0, stream>>>(P, Wpt, be, bv, bp, ZCs, comb);
  k_mlp1      <<<dim3(64, 8), 256, 0, stream>>>(comb, W1t, b1, hbuf);
  k_mlp2      <<<dim3(64, 4), 256, 0, stream>>>(hbuf, W2t, b2, out);
}